// Round 15
// baseline (41.814 us; speedup 1.0000x reference)
//
#include <hip/hip_runtime.h>

typedef __attribute__((ext_vector_type(8))) short    bf16x8;
typedef __attribute__((ext_vector_type(4))) float    f32x4;
typedef __attribute__((ext_vector_type(4))) float    float4_t;
typedef __attribute__((ext_vector_type(4))) unsigned u32x4;

constexpr int NSAMP    = 32768;
constexpr int INSZ     = 255;
constexpr int DIM      = 256;      // IN_SIZE + bias
constexpr int NSPLIT   = 1023;
constexpr int NCOL     = 1024;     // 1023 split cols + W as col 1023
constexpr int BM       = 64;       // samples per block
constexpr int NTHREADS = 512;      // 8 waves
constexpr int NMT      = 4;        // M-tiles per wave
constexpr int NPASS    = 8;        // col-tile passes per wave (64 tiles / 8 waves)

// LDS (exactly 160 KiB, 1 block/CU):
//  [0, 32768)      : x tile bf16 [64][256], byte ^= (row&7)<<4
//                    (reused as part[8][64] f32 AFTER phase 1 completes)
//  [32768, 163840) : XA_T bf16 [node 0..1023][sample 0..63]
//                    byte = node*128 + ((sample*2) ^ sw(node)),
//                    sw(node) = ((node&15)<<3) | ((node&1)<<2)
//                    -> 2 lanes/bank (free) on MFMA-output stores AND walk reads
constexpr int XA_OFF    = 32768;
constexpr int LDS_BYTES = XA_OFF + NCOL * 128;          // 163840
constexpr size_t WS_NEED = (size_t)NCOL * DIM * 2;      // 512 KiB bf16 fragment buffer

extern __shared__ char smem[];

// NOTE (r2/r6/r9/r10 lesson): inline-asm v_cvt_pk_bf16_f32 on MFMA ACCUMULATOR
// outputs produces NaN (missing MFMA->VALU hazard nops). f2bf (compiler code)
// is safe on accumulators; cvt_pk only on load-produced VGPR data (prep_frag).
__device__ __forceinline__ short f2bf(float f) {
  unsigned x = __builtin_bit_cast(unsigned, f);
  x += 0x7fffu + ((x >> 16) & 1u);            // RNE
  return (short)(x >> 16);
}
__device__ __forceinline__ float bfraw(unsigned hw16) {
  return __builtin_bit_cast(float, hw16 << 16);
}
__device__ __forceinline__ unsigned cvt_pk(float lo, float hi) {
  unsigned r;
  asm("v_cvt_pk_bf16_f32 %0, %1, %2" : "=v"(r) : "v"(lo), "v"(hi));
  return r;
}
__device__ __forceinline__ float clamp01(float v) {
  return fminf(fmaxf(v, 0.f), 1.f);
}

__device__ __forceinline__ int xat_sw(int node) {
  return ((node & 15) << 3) | ((node & 1) << 2);
}
// read XA_T[t][lane]: all lanes same node t -> 128B XOR'd span, 2 lanes/bank
__device__ __forceinline__ float xat_read(const char* __restrict__ xat, int t, int lane2) {
  unsigned hw = *(const unsigned short*)(xat + t * 128 + (lane2 ^ xat_sw(t)));
  return bfraw(hw);
}

// ---------------- prep: A (f32) + W row -> bf16 MFMA-fragment layout in d_ws ------------
// u32x4 index = ct*512 + ks*64 + lane
// holds A[col = ct*16 + (lane&15)][k = ks*32 + (lane>>4)*8 .. +8)  (col 1023 -> W[0:256))
__global__ void prep_frag(const float* __restrict__ A, const float* __restrict__ W,
                          u32x4* __restrict__ wsf)
{
  int t    = blockIdx.x * 128 + threadIdx.x;      // 0..32767 (256 blocks x 128 thr)
  int lane = t & 63;
  int ks   = (t >> 6) & 7;
  int ct   = t >> 9;
  int col  = ct * 16 + (lane & 15);
  int k0   = ks * 32 + ((lane >> 4) << 3);
  const float* src = (col < NSPLIT) ? (A + col * DIM + k0) : (W + k0);
  float4_t a0 = *(const float4_t*)src;
  float4_t a1 = *(const float4_t*)(src + 4);
  u32x4 p;
  p[0] = cvt_pk(a0[0], a0[1]);
  p[1] = cvt_pk(a0[2], a0[3]);
  p[2] = cvt_pk(a1[0], a1[1]);
  p[3] = cvt_pk(a1[2], a1[3]);
  wsf[t] = p;
}

// ---------------- B-fragment load (one col-tile, all 8 k-steps) ----------------
template<bool USE_WS>
__device__ __forceinline__ void load_bfr(int ct, bf16x8* dst, int lane,
                                         const u32x4* __restrict__ wsf,
                                         const float* __restrict__ A,
                                         const float* __restrict__ W)
{
  if constexpr (USE_WS) {
    const u32x4* fp = wsf + ct * 512 + lane;
#pragma unroll
    for (int ks = 0; ks < 8; ++ks)
      dst[ks] = __builtin_bit_cast(bf16x8, fp[ks * 64]);
  } else {
    int col = ct * 16 + (lane & 15);
    int k0  = (lane >> 4) << 3;
    const float* ap = (col < NSPLIT) ? (A + col * DIM) : W;
#pragma unroll
    for (int ks = 0; ks < 8; ++ks) {
      float4_t a0 = *(const float4_t*)(ap + ks * 32 + k0);
      float4_t a1 = *(const float4_t*)(ap + ks * 32 + k0 + 4);
      unsigned q0 = ((unsigned)(unsigned short)f2bf(a0[0])) | (((unsigned)(unsigned short)f2bf(a0[1])) << 16);
      unsigned q1 = ((unsigned)(unsigned short)f2bf(a0[2])) | (((unsigned)(unsigned short)f2bf(a0[3])) << 16);
      unsigned q2 = ((unsigned)(unsigned short)f2bf(a1[0])) | (((unsigned)(unsigned short)f2bf(a1[1])) << 16);
      unsigned q3 = ((unsigned)(unsigned short)f2bf(a1[2])) | (((unsigned)(unsigned short)f2bf(a1[3])) << 16);
      u32x4 p = {q0, q1, q2, q3};
      dst[ks] = __builtin_bit_cast(bf16x8, p);
    }
  }
}

// ---------------- two-chain interleaved ballot-DFS: lane = sample ----------------
// Two independent subtree chains stepped in lockstep: each step issues 2
// independent LDS reads -> exposed latency per node halves vs single-chain DFS.
// Ballot-prune at D>1 (both subtrees dead everywhere); leaves (D==1) branchless
// (r12/r14: ballot+branch >= the unconditional leaf body).
// t0/t1 are wave-uniform (derived from readfirstlane'd root) -> SGPR indices,
// scalar Wz loads.
template<int D>
__device__ __forceinline__ void dfs2(int t0, float q0, int t1, float q1,
                                     float& acc, const char* __restrict__ xat,
                                     int lane2, const float* __restrict__ Wz)
{
  if constexpr (D > 1) {
    if (__ballot(fmaxf(q0, q1) > 0.f) == 0ull) return;
  }
  float xa0 = xat_read(xat, t0, lane2);
  float xa1 = xat_read(xat, t1, lane2);
  float qL0 = fminf(q0, xa0), qR0 = fminf(q0, -xa0);
  float qL1 = fminf(q1, xa1), qR1 = fminf(q1, -xa1);
  acc += clamp01(qL0) * Wz[2 * t0 + 1] + clamp01(qR0) * Wz[2 * t0 + 2]
       + clamp01(qL1) * Wz[2 * t1 + 1] + clamp01(qR1) * Wz[2 * t1 + 2];
  if constexpr (D > 1) {
    dfs2<D - 1>(2 * t0 + 1, qL0, 2 * t1 + 1, qL1, acc, xat, lane2, Wz);
    dfs2<D - 1>(2 * t0 + 2, qR0, 2 * t1 + 2, qR1, acc, xat, lane2, Wz);
  }
}

// ---------------- fused main kernel ----------------
// 1 block/CU (160 KiB LDS) = 8 waves = 2 waves/EU. __launch_bounds__(512, 2):
// 2nd arg (min waves/EU = 2) sets the allocator budget to 256 registers (r14:
// verified win vs the amdgpu_waves_per_eu attribute, which does NOT do this).
template<bool USE_WS>
__global__ __launch_bounds__(NTHREADS, 2)
void lt_main(const float* __restrict__ X, const float* __restrict__ A,
             const float* __restrict__ W, const float* __restrict__ Bv,
             const u32x4* __restrict__ wsf, float* __restrict__ Out)
{
  const int tid  = threadIdx.x;
  const int lane = tid & 63;
  const int wave = tid >> 6;
  const int m0   = blockIdx.x * BM;

  // ---- issue pass-0 B fragments early (L2 latency overlaps X staging) ----
  bf16x8 b0[8], b1[8];
  load_bfr<USE_WS>(wave, b0, lane, wsf, A, W);

  // ---- stage x tile: contiguous 64*255 f32 region, float4 loads ----
  {
    const float4_t* Xt = (const float4_t*)(X + (size_t)m0 * INSZ);
#pragma unroll
    for (int i = 0; i < 8; ++i) {
      int idx = tid + i * NTHREADS;
      if (idx < 4080) {                      // 64*255/4
        float4_t v = Xt[idx];
#pragma unroll
        for (int e = 0; e < 4; ++e) {
          int g   = idx * 4 + e;
          int row = g / 255;
          int col = g - row * 255;
          *(short*)(smem + (((row << 9) + (col << 1)) ^ ((row & 7) << 4))) = f2bf(v[e]);
        }
      }
    }
    if (tid < BM)                            // bias column (=1.0)
      *(short*)(smem + (((tid << 9) + (255 << 1)) ^ ((tid & 7) << 4))) = (short)0x3f80;
  }
  __syncthreads();

  // ---- preload x fragments: 4 M-tiles x 8 K-steps (128 VGPR) ----
  bf16x8 xf[NMT][8];
#pragma unroll
  for (int mt = 0; mt < NMT; ++mt) {
    int row = mt * 16 + (lane & 15);
#pragma unroll
    for (int ks = 0; ks < 8; ++ks) {
      int kk = ks * 32 + ((lane >> 4) << 3);
      xf[mt][ks] = *(const bf16x8*)(smem + (((row << 9) + (kk << 1)) ^ ((row & 7) << 4)));
    }
  }
  // no barrier: phase 1 writes only the XA_T region, x tile stays intact

  char* xat = smem + XA_OFF;

  // ---- phase 1: 8 passes; wave owns col-tile ct = p*8 + wave ----
#pragma unroll
  for (int p = 0; p < NPASS; ++p) {
    bf16x8* cur = (p & 1) ? b1 : b0;
    bf16x8* nxt = (p & 1) ? b0 : b1;
    if (p < NPASS - 1)
      load_bfr<USE_WS>((p + 1) * 8 + wave, nxt, lane, wsf, A, W);   // prefetch next

    f32x4 acc[NMT];
#pragma unroll
    for (int mt = 0; mt < NMT; ++mt) acc[mt] = f32x4{0.f, 0.f, 0.f, 0.f};
#pragma unroll
    for (int ks = 0; ks < 8; ++ks) {
#pragma unroll
      for (int mt = 0; mt < NMT; ++mt)
        acc[mt] = __builtin_amdgcn_mfma_f32_16x16x32_bf16(xf[mt][ks], cur[ks], acc[mt], 0, 0, 0);
    }

    // write XA_T[node][sample]: node = ct*16 + (lane&15); 2 samples per u32 store
    // (f2bf-based pack -- see NOTE at f2bf about the cvt_pk-on-accumulator hazard)
    int node = (p * 8 + wave) * 16 + (lane & 15);
    int sw   = xat_sw(node);
    char* xrow = xat + node * 128;
#pragma unroll
    for (int mt = 0; mt < NMT; ++mt) {
#pragma unroll
      for (int h = 0; h < 2; ++h) {
        int s0 = mt * 16 + ((lane >> 4) << 2) + h * 2;
        unsigned lo = (unsigned short)f2bf(acc[mt][2 * h]);
        unsigned hi = (unsigned short)f2bf(acc[mt][2 * h + 1]);
        *(unsigned*)(xrow + ((s0 * 2) ^ sw)) = lo | (hi << 16);
      }
    }
  }
  __syncthreads();

  // ---- phase 2: transposed walk, lane = sample, two interleaved chains ----
  const float* Wz    = W + DIM;
  const int    lane2 = lane << 1;

  // readfirstlane: s3 is wave-uniform by construction but the compiler can't
  // prove it -> force SGPR so all node ids / Wz addresses go scalar.
  int s3 = __builtin_amdgcn_readfirstlane(7 + wave);   // level-3 subtree root
  int a2 = (s3 - 1) >> 1;                    // level-2 ancestor
  int a1 = (a2 - 1) >> 1;                    // level-1 ancestor
  float q = 1.f;
  {
    float x0 = xat_read(xat, 0,  lane2); q = fminf(q, (a1 & 1) ? x0 : -x0);
    float x1 = xat_read(xat, a1, lane2); q = fminf(q, (a2 & 1) ? x1 : -x1);
    float x2 = xat_read(xat, a2, lane2); q = fminf(q, (s3 & 1) ? x2 : -x2);
  }
  float acc = 0.f;
  {
    // visit s3, then two depth-6 children subtrees as interleaved chains
    float xa = xat_read(xat, s3, lane2);
    float qL = fminf(q, xa), qR = fminf(q, -xa);
    acc += clamp01(qL) * Wz[2 * s3 + 1] + clamp01(qR) * Wz[2 * s3 + 2];
    dfs2<6>(2 * s3 + 1, qL, 2 * s3 + 2, qR, acc, xat, lane2, Wz);
  }
  if (wave == 0) {
    // top tree: node 0, then subtrees {1},{2} interleaved (covers z-nodes 1..14)
    float x0 = xat_read(xat, 0, lane2);
    float l = fminf(1.f, x0), r = fminf(1.f, -x0);
    acc += clamp01(l) * Wz[1] + clamp01(r) * Wz[2];
    dfs2<2>(1, l, 2, r, acc, xat, lane2, Wz);
  }

  // ---- cross-wave reduction via x-tile region (dead: phase 1 is complete) ----
  float* part = (float*)smem;
  part[(wave << 6) + lane] = acc;
  __syncthreads();

  if (tid < BM) {
    float sum = 0.f;
#pragma unroll
    for (int w = 0; w < 8; ++w) sum += part[(w << 6) + tid];
    float xw = xat_read(xat, 1023, tid << 1);       // x.Wx from MFMA col 1023
    float v  = sum + xw + Bv[0] + Wz[0];            // + b + root weight (z0 = 1)
    Out[m0 + tid] = 1.f / (1.f + __expf(-v));
  }
}

extern "C" void kernel_launch(void* const* d_in, const int* in_sizes, int n_in,
                              void* d_out, int out_size, void* d_ws, size_t ws_size,
                              hipStream_t stream) {
  (void)in_sizes; (void)n_in; (void)out_size;
  const float* X  = (const float*)d_in[0];
  const float* A  = (const float*)d_in[1];
  const float* W  = (const float*)d_in[2];
  const float* Bv = (const float*)d_in[3];
  float* Out = (float*)d_out;

  const bool use_ws = (d_ws != nullptr) && (ws_size >= WS_NEED);
  if (use_ws) {
    prep_frag<<<256, 128, 0, stream>>>(A, W, (u32x4*)d_ws);
    hipFuncSetAttribute(reinterpret_cast<const void*>(lt_main<true>),
                        hipFuncAttributeMaxDynamicSharedMemorySize, LDS_BYTES);
    lt_main<true><<<NSAMP / BM, NTHREADS, LDS_BYTES, stream>>>(
        X, A, W, Bv, (const u32x4*)d_ws, Out);
  } else {
    hipFuncSetAttribute(reinterpret_cast<const void*>(lt_main<false>),
                        hipFuncAttributeMaxDynamicSharedMemorySize, LDS_BYTES);
    lt_main<false><<<NSAMP / BM, NTHREADS, LDS_BYTES, stream>>>(
        X, A, W, Bv, nullptr, Out);
  }
}

// Round 16
// 40.671 us; speedup vs baseline: 1.0281x; 1.0281x over previous
//
#include <hip/hip_runtime.h>

typedef __attribute__((ext_vector_type(8))) short    bf16x8;
typedef __attribute__((ext_vector_type(4))) float    f32x4;
typedef __attribute__((ext_vector_type(4))) float    float4_t;
typedef __attribute__((ext_vector_type(4))) unsigned u32x4;

constexpr int NSAMP    = 32768;
constexpr int INSZ     = 255;
constexpr int DIM      = 256;      // IN_SIZE + bias
constexpr int NSPLIT   = 1023;
constexpr int NCOL     = 1024;     // 1023 split cols + W as col 1023
constexpr int BM       = 32;       // samples per block
constexpr int NTHREADS = 256;      // 4 waves
constexpr int NMT      = 2;        // M-tiles per wave
constexpr int NPASS    = 16;       // col-tile passes per wave (64 tiles / 4 waves)

// LDS (80 KiB/block -> 2 blocks/CU; cross-block phase overlap):
//  [0, 16384)     : x tile bf16 [32][256], byte ^= (row&7)<<4
//                   (reused as part f32[256] AFTER phase 1 completes)
//  [16384, 81920) : XA_T bf16 [node 0..1023][sample 0..31]
//                   byte = node*64 + ((s*2) ^ sw(node)),
//                   sw(node) = ((n&7)<<3) | (((n>>3)&1)<<2)
//                   -> ~2 lanes/bank on MFMA stores; conflict-free walk reads
//                   (odd/even subtree roots hit disjoint bank halves)
constexpr int XA_OFF    = 16384;
constexpr int LDS_BYTES = XA_OFF + NCOL * 64;           // 81920
constexpr size_t WS_NEED = (size_t)NCOL * DIM * 2;      // 512 KiB bf16 fragment buffer

extern __shared__ char smem[];

// NOTE (r2/r6/r9/r10 lesson): inline-asm v_cvt_pk_bf16_f32 on MFMA ACCUMULATOR
// outputs produces NaN (missing MFMA->VALU hazard nops). f2bf (compiler code)
// is safe on accumulators; cvt_pk only on load-produced VGPR data (prep_frag).
__device__ __forceinline__ short f2bf(float f) {
  unsigned x = __builtin_bit_cast(unsigned, f);
  x += 0x7fffu + ((x >> 16) & 1u);            // RNE
  return (short)(x >> 16);
}
__device__ __forceinline__ float bfraw(unsigned hw16) {
  return __builtin_bit_cast(float, hw16 << 16);
}
__device__ __forceinline__ unsigned cvt_pk(float lo, float hi) {
  unsigned r;
  asm("v_cvt_pk_bf16_f32 %0, %1, %2" : "=v"(r) : "v"(lo), "v"(hi));
  return r;
}
__device__ __forceinline__ float clamp01(float v) {
  return fminf(fmaxf(v, 0.f), 1.f);
}

__device__ __forceinline__ int xat_sw(int node) {
  return ((node & 7) << 3) | (((node >> 3) & 1) << 2);
}
// read XA_T[t][s]: s2 = s*2 (byte offset within 64B row)
__device__ __forceinline__ float xat_read(const char* __restrict__ xat, int t, int s2) {
  unsigned hw = *(const unsigned short*)(xat + t * 64 + (s2 ^ xat_sw(t)));
  return bfraw(hw);
}

// ---------------- prep: A (f32) + W row -> bf16 MFMA-fragment layout in d_ws ------------
// u32x4 index = ct*512 + ks*64 + lane
// holds A[col = ct*16 + (lane&15)][k = ks*32 + (lane>>4)*8 .. +8)  (col 1023 -> W[0:256))
__global__ void prep_frag(const float* __restrict__ A, const float* __restrict__ W,
                          u32x4* __restrict__ wsf)
{
  int t    = blockIdx.x * 512 + threadIdx.x;      // 0..32767
  int lane = t & 63;
  int ks   = (t >> 6) & 7;
  int ct   = t >> 9;
  int col  = ct * 16 + (lane & 15);
  int k0   = ks * 32 + ((lane >> 4) << 3);
  const float* src = (col < NSPLIT) ? (A + col * DIM + k0) : (W + k0);
  float4_t a0 = *(const float4_t*)src;
  float4_t a1 = *(const float4_t*)(src + 4);
  u32x4 p;
  p[0] = cvt_pk(a0[0], a0[1]);
  p[1] = cvt_pk(a0[2], a0[3]);
  p[2] = cvt_pk(a1[0], a1[1]);
  p[3] = cvt_pk(a1[2], a1[3]);
  wsf[t] = p;
}

// ---------------- B-fragment load (one col-tile, all 8 k-steps) ----------------
template<bool USE_WS>
__device__ __forceinline__ void load_bfr(int ct, bf16x8* dst, int lane,
                                         const u32x4* __restrict__ wsf,
                                         const float* __restrict__ A,
                                         const float* __restrict__ W)
{
  if constexpr (USE_WS) {
    const u32x4* fp = wsf + ct * 512 + lane;
#pragma unroll
    for (int ks = 0; ks < 8; ++ks)
      dst[ks] = __builtin_bit_cast(bf16x8, fp[ks * 64]);
  } else {
    int col = ct * 16 + (lane & 15);
    int k0  = (lane >> 4) << 3;
    const float* ap = (col < NSPLIT) ? (A + col * DIM) : W;
#pragma unroll
    for (int ks = 0; ks < 8; ++ks) {
      float4_t a0 = *(const float4_t*)(ap + ks * 32 + k0);
      float4_t a1 = *(const float4_t*)(ap + ks * 32 + k0 + 4);
      unsigned q0 = ((unsigned)(unsigned short)f2bf(a0[0])) | (((unsigned)(unsigned short)f2bf(a0[1])) << 16);
      unsigned q1 = ((unsigned)(unsigned short)f2bf(a0[2])) | (((unsigned)(unsigned short)f2bf(a0[3])) << 16);
      unsigned q2 = ((unsigned)(unsigned short)f2bf(a1[0])) | (((unsigned)(unsigned short)f2bf(a1[1])) << 16);
      unsigned q3 = ((unsigned)(unsigned short)f2bf(a1[2])) | (((unsigned)(unsigned short)f2bf(a1[3])) << 16);
      u32x4 p = {q0, q1, q2, q3};
      dst[ks] = __builtin_bit_cast(bf16x8, p);
    }
  }
}

// ---------------- ballot-DFS walk (r14-verified local optimum) ----------------
// lane = (half, sample): t is per-lane (differs between halves). Prune at D>1
// when ALL 64 lanes (both subtrees) dead; leaves (D==1) branchless.
template<int D>
__device__ __forceinline__ void dfs(int t, float q, float& acc,
                                    const char* __restrict__ xat, int s2,
                                    const float* __restrict__ Wz)
{
  if constexpr (D > 1) {
    if (__ballot(q > 0.f) == 0ull) return;
  }
  float xa = xat_read(xat, t, s2);
  float qL = fminf(q, xa);          // child 2t+1 (odd, left, +)
  float qR = fminf(q, -xa);         // child 2t+2 (even, right, -)
  acc += clamp01(qL) * Wz[2 * t + 1] + clamp01(qR) * Wz[2 * t + 2];
  if constexpr (D > 1) {
    dfs<D - 1>(2 * t + 1, qL, acc, xat, s2, Wz);
    dfs<D - 1>(2 * t + 2, qR, acc, xat, s2, Wz);
  }
}

// ---------------- fused main kernel ----------------
// 80 KiB LDS -> 2 independent blocks/CU: one block's walk/staging overlaps the
// other's MFMA. 4 waves/block -> 8 waves/CU = 2/EU; __launch_bounds__(256, 2)
// sets the 256-register allocator budget (r14-verified mechanism).
template<bool USE_WS>
__global__ __launch_bounds__(NTHREADS, 2)
void lt_main(const float* __restrict__ X, const float* __restrict__ A,
             const float* __restrict__ W, const float* __restrict__ Bv,
             const u32x4* __restrict__ wsf, float* __restrict__ Out)
{
  const int tid  = threadIdx.x;
  const int lane = tid & 63;
  const int wave = tid >> 6;
  const int m0   = blockIdx.x * BM;

  // ---- issue pass-0 B fragments early (L2 latency overlaps X staging) ----
  bf16x8 b0[8], b1[8];
  load_bfr<USE_WS>(wave, b0, lane, wsf, A, W);

  // ---- stage x tile: contiguous 32*255 f32 region, float4 loads ----
  {
    const float4_t* Xt = (const float4_t*)(X + (size_t)m0 * INSZ);
#pragma unroll
    for (int i = 0; i < 8; ++i) {
      int idx = tid + i * NTHREADS;
      if (idx < 2040) {                      // 32*255/4
        float4_t v = Xt[idx];
#pragma unroll
        for (int e = 0; e < 4; ++e) {
          int g   = idx * 4 + e;
          int row = g / 255;
          int col = g - row * 255;
          *(short*)(smem + (((row << 9) + (col << 1)) ^ ((row & 7) << 4))) = f2bf(v[e]);
        }
      }
    }
    if (tid < BM)                            // bias column (=1.0)
      *(short*)(smem + (((tid << 9) + (255 << 1)) ^ ((tid & 7) << 4))) = (short)0x3f80;
  }
  __syncthreads();

  // ---- preload x fragments: 2 M-tiles x 8 K-steps (32 VGPR) ----
  bf16x8 xf[NMT][8];
#pragma unroll
  for (int mt = 0; mt < NMT; ++mt) {
    int row = mt * 16 + (lane & 15);
#pragma unroll
    for (int ks = 0; ks < 8; ++ks) {
      int kk = ks * 32 + ((lane >> 4) << 3);
      xf[mt][ks] = *(const bf16x8*)(smem + (((row << 9) + (kk << 1)) ^ ((row & 7) << 4)));
    }
  }
  // no barrier: phase 1 writes only the XA_T region, x tile stays intact

  char* xat = smem + XA_OFF;

  // ---- phase 1: 16 passes; wave owns col-tile ct = p*4 + wave ----
#pragma unroll
  for (int p = 0; p < NPASS; ++p) {
    bf16x8* cur = (p & 1) ? b1 : b0;
    bf16x8* nxt = (p & 1) ? b0 : b1;
    if (p < NPASS - 1)
      load_bfr<USE_WS>((p + 1) * 4 + wave, nxt, lane, wsf, A, W);   // prefetch next

    f32x4 acc[NMT];
#pragma unroll
    for (int mt = 0; mt < NMT; ++mt) acc[mt] = f32x4{0.f, 0.f, 0.f, 0.f};
#pragma unroll
    for (int ks = 0; ks < 8; ++ks) {
#pragma unroll
      for (int mt = 0; mt < NMT; ++mt)
        acc[mt] = __builtin_amdgcn_mfma_f32_16x16x32_bf16(xf[mt][ks], cur[ks], acc[mt], 0, 0, 0);
    }

    // write XA_T[node][sample]: node = ct*16 + (lane&15); 2 samples per u32 store
    // (f2bf pack -- see NOTE at f2bf about the cvt_pk-on-accumulator hazard)
    int node = (p * 4 + wave) * 16 + (lane & 15);
    int sw   = xat_sw(node);
    char* xrow = xat + node * 64;
#pragma unroll
    for (int mt = 0; mt < NMT; ++mt) {
#pragma unroll
      for (int h = 0; h < 2; ++h) {
        int s0 = mt * 16 + ((lane >> 4) << 2) + h * 2;
        unsigned lo = (unsigned short)f2bf(acc[mt][2 * h]);
        unsigned hi = (unsigned short)f2bf(acc[mt][2 * h + 1]);
        *(unsigned*)(xrow + ((s0 * 2) ^ sw)) = lo | (hi << 16);
      }
    }
  }
  __syncthreads();

  // ---- phase 2: walk; lanes 0-31 = subtree 7+2*wave, lanes 32-63 = 8+2*wave ----
  const float* Wz = W + DIM;
  const int    s2 = (lane & 31) << 1;        // sample byte offset

  int tr = ((lane < 32) ? 7 : 8) + 2 * wave; // this half's level-3 subtree root
  int a2 = (tr - 1) >> 1;                    // level-2 ancestor
  int a1 = (a2 - 1) >> 1;                    // level-1 ancestor
  float q = 1.f;
  {
    float x0 = xat_read(xat, 0,  s2); q = fminf(q, (a1 & 1) ? x0 : -x0);
    float x1 = xat_read(xat, a1, s2); q = fminf(q, (a2 & 1) ? x1 : -x1);
    float x2 = xat_read(xat, a2, s2); q = fminf(q, (tr & 1) ? x2 : -x2);
  }
  float acc = 0.f;
  dfs<7>(tr, q, acc, xat, s2, Wz);           // z-nodes of this half's subtree
  if (wave == 0) {
    // top tree: z 1..14. Halves take node 0's children 1 / 2 respectively.
    float x0 = xat_read(xat, 0, s2);
    float qh = (lane < 32) ? fminf(1.f, x0) : fminf(1.f, -x0);
    int   ch = (lane < 32) ? 1 : 2;
    acc += clamp01(qh) * Wz[ch];
    dfs<2>(ch, qh, acc, xat, s2, Wz);        // z 3,4,7..10 | z 5,6,11..14
  }

  // ---- cross-wave reduction via x-tile region (dead: phase 1 is complete) ----
  float* part = (float*)smem;
  part[tid] = acc;                           // part[(wave,half)][sample] flat
  __syncthreads();

  if (tid < BM) {
    float sum = 0.f;
#pragma unroll
    for (int j = 0; j < 8; ++j) sum += part[j * 32 + tid];
    float xw = xat_read(xat, 1023, tid << 1);       // x.Wx from MFMA col 1023
    float v  = sum + xw + Bv[0] + Wz[0];            // + b + root weight (z0 = 1)
    Out[m0 + tid] = 1.f / (1.f + __expf(-v));
  }
}

extern "C" void kernel_launch(void* const* d_in, const int* in_sizes, int n_in,
                              void* d_out, int out_size, void* d_ws, size_t ws_size,
                              hipStream_t stream) {
  (void)in_sizes; (void)n_in; (void)out_size;
  const float* X  = (const float*)d_in[0];
  const float* A  = (const float*)d_in[1];
  const float* W  = (const float*)d_in[2];
  const float* Bv = (const float*)d_in[3];
  float* Out = (float*)d_out;

  const bool use_ws = (d_ws != nullptr) && (ws_size >= WS_NEED);
  if (use_ws) {
    prep_frag<<<64, 512, 0, stream>>>(A, W, (u32x4*)d_ws);
    hipFuncSetAttribute(reinterpret_cast<const void*>(lt_main<true>),
                        hipFuncAttributeMaxDynamicSharedMemorySize, LDS_BYTES);
    lt_main<true><<<NSAMP / BM, NTHREADS, LDS_BYTES, stream>>>(
        X, A, W, Bv, (const u32x4*)d_ws, Out);
  } else {
    hipFuncSetAttribute(reinterpret_cast<const void*>(lt_main<false>),
                        hipFuncAttributeMaxDynamicSharedMemorySize, LDS_BYTES);
    lt_main<false><<<NSAMP / BM, NTHREADS, LDS_BYTES, stream>>>(
        X, A, W, Bv, nullptr, Out);
  }
}